// Round 4
// baseline (487.920 us; speedup 1.0000x reference)
//
#include <hip/hip_runtime.h>

#define FEPS 1e-5f

constexpr int Bn = 4, Hn = 16, Sn = 4096, Dn = 64;
constexpr int NHEAD = Bn * Hn;          // 64 heads
constexpr int WSTG = 8;                 // rows per stage per wave
constexpr int SLOT = Dn * Dn + Dn;      // 4160 floats: kv then ksum

// direct global->LDS, 16B per lane (dest = wave-uniform base + lane*16)
__device__ __forceinline__ void gload16(const float* g, float* l) {
    __builtin_amdgcn_global_load_lds(
        (const __attribute__((address_space(1))) void*)g,
        (__attribute__((address_space(3))) void*)l,
        16, 0, 0);
}

// wave-private wait: vmcnt is per-wave, so no barrier needed for our own
// global_load_lds writes into our own LDS slice. sched_barrier pins order.
template <int N>
__device__ __forceinline__ void vmwait() {
    if constexpr (N == 0) asm volatile("s_waitcnt vmcnt(0)" ::: "memory");
    else                  asm volatile("s_waitcnt vmcnt(4)" ::: "memory");
    __builtin_amdgcn_sched_barrier(0);
}

// ---------------- Pass 1: partial kv = K^T V and k_sum over an S-chunk ----------------
// 4 waves per block, each wave: private S-range, private double-buffered LDS
// slice, private vmcnt-counted pipeline. NO per-stage __syncthreads. One
// barrier at the end for the cross-wave kv reduction.
__global__ __launch_bounds__(256, 4) void pass1(const float* __restrict__ K,
                                                const float* __restrict__ V,
                                                float* __restrict__ part,
                                                int ch_s) {
    __shared__ float lds[4][2][2][WSTG][Dn];   // [wave][buf][K/V][row][d] = 32 KB
    __shared__ float ksred[4][Dn];             // 1 KB

    const int head = blockIdx.x;
    const int chunk = blockIdx.y;
    const int t = threadIdx.x;
    const int w = t >> 6;                  // wave 0..3
    const int l = t & 63;
    const int d0 = (l >> 3) * 8;           // kv row-tile base (K dim)
    const int e0 = (l & 7) * 8;            // kv col-tile base (V dim)
    const int rows_per_wave = ch_s >> 2;
    const int nstg = rows_per_wave / WSTG;

    const size_t base = ((size_t)head * Sn + (size_t)chunk * ch_s) * Dn;
    const float* kw = K + base + (size_t)w * rows_per_wave * Dn + l * 4;  // per-lane src
    const float* vw = V + base + (size_t)w * rows_per_wave * Dn + l * 4;

    float acc[8][8] = {};
    float ks[8] = {};

    auto STAGE = [&](int s, int b) {
        const float* kp = kw + s * (WSTG * Dn);
        const float* vp = vw + s * (WSTG * Dn);
        float* kl = &lds[w][b][0][0][0];   // wave-uniform LDS dest
        float* vl = &lds[w][b][1][0][0];
        gload16(kp, kl);
        gload16(kp + 256, kl + 256);
        gload16(vp, vl);
        gload16(vp + 256, vl + 256);
    };

    STAGE(0, 0);
    STAGE(1, 1);

    for (int st = 0; st < nstg; ++st) {
        const int cur = st & 1;
        if (st + 1 < nstg) vmwait<4>();    // stage st landed; st+1 stays in flight
        else               vmwait<0>();    // tail: drain
        const float* kb = &lds[w][cur][0][0][0];
        const float* vb = &lds[w][cur][1][0][0];
        #pragma unroll
        for (int r = 0; r < WSTG; ++r) {
            float4 ka = *(const float4*)(kb + r * Dn + d0);
            float4 kc = *(const float4*)(kb + r * Dn + d0 + 4);
            float4 va = *(const float4*)(vb + r * Dn + e0);
            float4 vc = *(const float4*)(vb + r * Dn + e0 + 4);
            float kf[8] = {ka.x, ka.y, ka.z, ka.w, kc.x, kc.y, kc.z, kc.w};
            float vf[8] = {va.x, va.y, va.z, va.w, vc.x, vc.y, vc.z, vc.w};
            #pragma unroll
            for (int i = 0; i < 8; ++i) {
                ks[i] += kf[i];
                #pragma unroll
                for (int j = 0; j < 8; ++j) acc[i][j] += kf[i] * vf[j];
            }
        }
        if (st + 2 < nstg) {
            __builtin_amdgcn_sched_barrier(0);   // keep refill after the reads above
            STAGE(st + 2, cur);                  // refill the buffer just consumed
        }
    }

    // ---- block reduction of the 4 wave partials (staging buffers now free) ----
    __syncthreads();
    float* redA = &lds[0][0][0][0][0];   // 4096 floats (waves 0-1 slices)
    float* redB = &lds[2][0][0][0][0];   // 4096 floats (waves 2-3 slices)
    if (w == 0 || w == 1) {
        float* dst = (w == 0) ? redA : redB;
        #pragma unroll
        for (int i = 0; i < 8; ++i) {
            *(float4*)&dst[(d0 + i) * Dn + e0] =
                make_float4(acc[i][0], acc[i][1], acc[i][2], acc[i][3]);
            *(float4*)&dst[(d0 + i) * Dn + e0 + 4] =
                make_float4(acc[i][4], acc[i][5], acc[i][6], acc[i][7]);
        }
    }
    if ((l & 7) == 0) {
        #pragma unroll
        for (int i = 0; i < 8; ++i) ksred[w][d0 + i] = ks[i];
    }
    __syncthreads();
    if (w == 2 || w == 3) {
        float* dst = (w == 2) ? redA : redB;
        #pragma unroll
        for (int i = 0; i < 8; ++i)
            #pragma unroll
            for (int j = 0; j < 8; ++j) dst[(d0 + i) * Dn + e0 + j] += acc[i][j];
    }
    __syncthreads();

    float* slot = part + ((size_t)chunk * NHEAD + head) * SLOT;
    #pragma unroll
    for (int q = 0; q < 4; ++q) {
        int f = q * 1024 + t * 4;          // coalesced across lanes
        float4 a = *(const float4*)&redA[f];
        float4 b = *(const float4*)&redB[f];
        *(float4*)&slot[f] = make_float4(a.x + b.x, a.y + b.y, a.z + b.z, a.w + b.w);
    }
    if (t < Dn)
        slot[Dn * Dn + t] = ksred[0][t] + ksred[1][t] + ksred[2][t] + ksred[3][t];
}

// ---------------- Reduce chunk-partials -> final slot layout [head][4096 kv + 64 ksum] ----------------
__global__ __launch_bounds__(256) void reduce_partials(const float* __restrict__ part,
                                                       float* __restrict__ slots,
                                                       int nchunks) {
    const int head = blockIdx.x;
    const int idx = blockIdx.y * 256 + threadIdx.x;
    if (idx >= SLOT) return;
    float s = 0.f;
    for (int c = 0; c < nchunks; ++c)
        s += part[((size_t)c * NHEAD + head) * SLOT + idx];
    slots[(size_t)head * SLOT + idx] = s;
}

// ---------------- Pass 2: out = (Q / (Q.ksum + eps)) @ kv ----------------
__global__ __launch_bounds__(256) void pass2(const float* __restrict__ Q,
                                             const float* __restrict__ slots,
                                             float* __restrict__ out) {
    const int head = blockIdx.x;
    const int rc = blockIdx.y;  // 64-row chunk
    const int t = threadIdx.x;
    const int ti = t >> 4, tj = t & 15;
    const int r0 = ti * 4, e0 = tj * 4;   // 4 rows x 4 cols per thread

    __shared__ float kvs[Dn][Dn];
    __shared__ float qT[Dn][68];          // transposed Q tile, padded
    __shared__ float kss[Dn];

    const float* kvh = slots + (size_t)head * SLOT;

    // stage kv (16KB; L2/L3-resident after reduce)
    const float4* kvsrc = (const float4*)kvh;
    float4* kvdst = (float4*)&kvs[0][0];
    #pragma unroll
    for (int kk = 0; kk < 4; ++kk) kvdst[t + 256 * kk] = kvsrc[t + 256 * kk];
    if (t < 16) ((float4*)kss)[t] = ((const float4*)(kvh + Dn * Dn))[t];

    // stage Q tile transposed: qT[d][row]
    const float4* Qsrc = (const float4*)(Q + ((size_t)head * Sn + (size_t)rc * 64) * Dn);
    #pragma unroll
    for (int kk = 0; kk < 4; ++kk) {
        int f = t + 256 * kk;
        int row = f >> 4, d4 = (f & 15) * 4;
        float4 q4 = Qsrc[f];
        qT[d4 + 0][row] = q4.x;
        qT[d4 + 1][row] = q4.y;
        qT[d4 + 2][row] = q4.z;
        qT[d4 + 3][row] = q4.w;
    }
    __syncthreads();

    float acc[4][4] = {};
    float dn[4] = {0.f, 0.f, 0.f, 0.f};
    #pragma unroll 8
    for (int d = 0; d < Dn; ++d) {
        float4 a = *(const float4*)&qT[d][r0];     // q for 4 rows at dim d
        float4 b = *(const float4*)&kvs[d][e0];    // kv row d, 4 cols
        float ksd = kss[d];
        float av[4] = {a.x, a.y, a.z, a.w};
        float bv[4] = {b.x, b.y, b.z, b.w};
        #pragma unroll
        for (int i = 0; i < 4; ++i) {
            dn[i] += av[i] * ksd;
            #pragma unroll
            for (int j = 0; j < 4; ++j) acc[i][j] += av[i] * bv[j];
        }
    }

    float* Oh = out + ((size_t)head * Sn + (size_t)rc * 64) * Dn;
    #pragma unroll
    for (int i = 0; i < 4; ++i) {
        float inv = 1.0f / (dn[i] + FEPS);
        float4 r;
        r.x = acc[i][0] * inv; r.y = acc[i][1] * inv;
        r.z = acc[i][2] * inv; r.w = acc[i][3] * inv;
        *(float4*)&Oh[(size_t)(r0 + i) * Dn + e0] = r;
    }
}

extern "C" void kernel_launch(void* const* d_in, const int* in_sizes, int n_in,
                              void* d_out, int out_size, void* d_ws, size_t ws_size,
                              hipStream_t stream) {
    (void)in_sizes; (void)n_in; (void)out_size;
    const float* Q = (const float*)d_in[0];
    const float* K = (const float*)d_in[1];
    const float* V = (const float*)d_in[2];
    float* out = (float*)d_out;

    float* slots = (float*)d_ws;                         // [64][4160] final kv+ksum

    // pick the largest chunk count whose partial buffer fits in d_ws
    int chunks = 1;
    const int cand[4] = {16, 8, 4, 2};
    for (int ci = 0; ci < 4; ++ci) {
        if ((size_t)(1 + cand[ci]) * NHEAD * SLOT * sizeof(float) <= ws_size) {
            chunks = cand[ci];
            break;
        }
    }

    if (chunks > 1) {
        float* part = slots + (size_t)NHEAD * SLOT;      // [chunks][64][4160]
        hipLaunchKernelGGL(pass1, dim3(NHEAD, chunks), dim3(256), 0, stream,
                           K, V, part, Sn / chunks);
        hipLaunchKernelGGL(reduce_partials, dim3(NHEAD, (SLOT + 255) / 256), dim3(256), 0, stream,
                           part, slots, chunks);
    } else {
        // one block per head writes the final slot directly (no reduce needed)
        hipLaunchKernelGGL(pass1, dim3(NHEAD, 1), dim3(256), 0, stream,
                           K, V, slots, Sn);
    }
    hipLaunchKernelGGL(pass2, dim3(NHEAD, Sn / 64), dim3(256), 0, stream,
                       Q, slots, out);
}

// Round 5
// 282.531 us; speedup vs baseline: 1.7270x; 1.7270x over previous
//
#include <hip/hip_runtime.h>

#define FEPS 1e-5f

constexpr int Bn = 4, Hn = 16, Sn = 4096, Dn = 64;
constexpr int NHEAD = Bn * Hn;          // 64 heads
constexpr int WSTG = 8;                 // rows per stage per wave
constexpr int SLOT = Dn * Dn + Dn;      // 4160 floats: kv then ksum

// direct global->LDS, 16B per lane (dest = wave-uniform base + lane*16)
__device__ __forceinline__ void gload16(const float* g, float* l) {
    __builtin_amdgcn_global_load_lds(
        (const __attribute__((address_space(1))) void*)g,
        (__attribute__((address_space(3))) void*)l,
        16, 0, 0);
}

// wave-private wait: vmcnt is per-wave, so no barrier needed for our own
// global_load_lds writes into our own LDS slice. sched_barrier pins order.
template <int N>
__device__ __forceinline__ void vmwait() {
    if constexpr (N == 0) asm volatile("s_waitcnt vmcnt(0)" ::: "memory");
    else                  asm volatile("s_waitcnt vmcnt(4)" ::: "memory");
    __builtin_amdgcn_sched_barrier(0);
}

// ---------------- Pass 1: partial kv = K^T V and k_sum over an S-chunk ----------------
// 4 waves per block, each wave: private S-range, private double-buffered LDS
// slice, private vmcnt-counted pipeline. NO per-stage __syncthreads. One
// barrier at the end for the cross-wave kv reduction.
// launch_bounds(256,3): R3 measured 84 VGPR spill-free at this bound; (256,4)
// capped VGPRs at 64 and spilled acc[8][8] -> 1.8 GB scratch traffic (R4).
__global__ __launch_bounds__(256, 3) void pass1(const float* __restrict__ K,
                                                const float* __restrict__ V,
                                                float* __restrict__ part,
                                                int ch_s) {
    __shared__ float lds[4][2][2][WSTG][Dn];   // [wave][buf][K/V][row][d] = 32 KB
    __shared__ float ksred[4][Dn];             // 1 KB

    const int head = blockIdx.x;
    const int chunk = blockIdx.y;
    const int t = threadIdx.x;
    const int w = t >> 6;                  // wave 0..3
    const int l = t & 63;
    const int d0 = (l >> 3) * 8;           // kv row-tile base (K dim)
    const int e0 = (l & 7) * 8;            // kv col-tile base (V dim)
    const int rows_per_wave = ch_s >> 2;
    const int nstg = rows_per_wave / WSTG;

    const size_t base = ((size_t)head * Sn + (size_t)chunk * ch_s) * Dn;
    const float* kw = K + base + (size_t)w * rows_per_wave * Dn + l * 4;  // per-lane src
    const float* vw = V + base + (size_t)w * rows_per_wave * Dn + l * 4;

    float acc[8][8] = {};
    float ks[8] = {};

    auto STAGE = [&](int s, int b) {
        const float* kp = kw + s * (WSTG * Dn);
        const float* vp = vw + s * (WSTG * Dn);
        float* kl = &lds[w][b][0][0][0];   // wave-uniform LDS dest
        float* vl = &lds[w][b][1][0][0];
        gload16(kp, kl);
        gload16(kp + 256, kl + 256);
        gload16(vp, vl);
        gload16(vp + 256, vl + 256);
    };

    STAGE(0, 0);
    STAGE(1, 1);

    for (int st = 0; st < nstg; ++st) {
        const int cur = st & 1;
        if (st + 1 < nstg) vmwait<4>();    // stage st landed; st+1 stays in flight
        else               vmwait<0>();    // tail: drain
        const float* kb = &lds[w][cur][0][0][0];
        const float* vb = &lds[w][cur][1][0][0];
        #pragma unroll
        for (int r = 0; r < WSTG; ++r) {
            float4 ka = *(const float4*)(kb + r * Dn + d0);
            float4 kc = *(const float4*)(kb + r * Dn + d0 + 4);
            float4 va = *(const float4*)(vb + r * Dn + e0);
            float4 vc = *(const float4*)(vb + r * Dn + e0 + 4);
            float kf[8] = {ka.x, ka.y, ka.z, ka.w, kc.x, kc.y, kc.z, kc.w};
            float vf[8] = {va.x, va.y, va.z, va.w, vc.x, vc.y, vc.z, vc.w};
            #pragma unroll
            for (int i = 0; i < 8; ++i) {
                ks[i] += kf[i];
                #pragma unroll
                for (int j = 0; j < 8; ++j) acc[i][j] += kf[i] * vf[j];
            }
        }
        if (st + 2 < nstg) {
            __builtin_amdgcn_sched_barrier(0);   // keep refill after the reads above
            STAGE(st + 2, cur);                  // refill the buffer just consumed
        }
    }

    // ---- block reduction of the 4 wave partials (staging buffers now free) ----
    __syncthreads();
    float* redA = &lds[0][0][0][0][0];   // 4096 floats (waves 0-1 slices)
    float* redB = &lds[2][0][0][0][0];   // 4096 floats (waves 2-3 slices)
    if (w == 0 || w == 1) {
        float* dst = (w == 0) ? redA : redB;
        #pragma unroll
        for (int i = 0; i < 8; ++i) {
            *(float4*)&dst[(d0 + i) * Dn + e0] =
                make_float4(acc[i][0], acc[i][1], acc[i][2], acc[i][3]);
            *(float4*)&dst[(d0 + i) * Dn + e0 + 4] =
                make_float4(acc[i][4], acc[i][5], acc[i][6], acc[i][7]);
        }
    }
    if ((l & 7) == 0) {
        #pragma unroll
        for (int i = 0; i < 8; ++i) ksred[w][d0 + i] = ks[i];
    }
    __syncthreads();
    if (w == 2 || w == 3) {
        float* dst = (w == 2) ? redA : redB;
        #pragma unroll
        for (int i = 0; i < 8; ++i)
            #pragma unroll
            for (int j = 0; j < 8; ++j) dst[(d0 + i) * Dn + e0 + j] += acc[i][j];
    }
    __syncthreads();

    float* slot = part + ((size_t)chunk * NHEAD + head) * SLOT;
    #pragma unroll
    for (int q = 0; q < 4; ++q) {
        int f = q * 1024 + t * 4;          // coalesced across lanes
        float4 a = *(const float4*)&redA[f];
        float4 b = *(const float4*)&redB[f];
        *(float4*)&slot[f] = make_float4(a.x + b.x, a.y + b.y, a.z + b.z, a.w + b.w);
    }
    if (t < Dn)
        slot[Dn * Dn + t] = ksred[0][t] + ksred[1][t] + ksred[2][t] + ksred[3][t];
}

// ---------------- Reduce chunk-partials -> final slot layout [head][4096 kv + 64 ksum] ----------------
__global__ __launch_bounds__(256) void reduce_partials(const float* __restrict__ part,
                                                       float* __restrict__ slots,
                                                       int nchunks) {
    const int head = blockIdx.x;
    const int idx = blockIdx.y * 256 + threadIdx.x;
    if (idx >= SLOT) return;
    float s = 0.f;
    for (int c = 0; c < nchunks; ++c)
        s += part[((size_t)c * NHEAD + head) * SLOT + idx];
    slots[(size_t)head * SLOT + idx] = s;
}

// ---------------- Pass 2: out = (Q / (Q.ksum + eps)) @ kv ----------------
__global__ __launch_bounds__(256) void pass2(const float* __restrict__ Q,
                                             const float* __restrict__ slots,
                                             float* __restrict__ out) {
    const int head = blockIdx.x;
    const int rc = blockIdx.y;  // 64-row chunk
    const int t = threadIdx.x;
    const int ti = t >> 4, tj = t & 15;
    const int r0 = ti * 4, e0 = tj * 4;   // 4 rows x 4 cols per thread

    __shared__ float kvs[Dn][Dn];
    __shared__ float qT[Dn][68];          // transposed Q tile, padded
    __shared__ float kss[Dn];

    const float* kvh = slots + (size_t)head * SLOT;

    // stage kv (16KB; L2/L3-resident after reduce)
    const float4* kvsrc = (const float4*)kvh;
    float4* kvdst = (float4*)&kvs[0][0];
    #pragma unroll
    for (int kk = 0; kk < 4; ++kk) kvdst[t + 256 * kk] = kvsrc[t + 256 * kk];
    if (t < 16) ((float4*)kss)[t] = ((const float4*)(kvh + Dn * Dn))[t];

    // stage Q tile transposed: qT[d][row]
    const float4* Qsrc = (const float4*)(Q + ((size_t)head * Sn + (size_t)rc * 64) * Dn);
    #pragma unroll
    for (int kk = 0; kk < 4; ++kk) {
        int f = t + 256 * kk;
        int row = f >> 4, d4 = (f & 15) * 4;
        float4 q4 = Qsrc[f];
        qT[d4 + 0][row] = q4.x;
        qT[d4 + 1][row] = q4.y;
        qT[d4 + 2][row] = q4.z;
        qT[d4 + 3][row] = q4.w;
    }
    __syncthreads();

    float acc[4][4] = {};
    float dn[4] = {0.f, 0.f, 0.f, 0.f};
    #pragma unroll 8
    for (int d = 0; d < Dn; ++d) {
        float4 a = *(const float4*)&qT[d][r0];     // q for 4 rows at dim d
        float4 b = *(const float4*)&kvs[d][e0];    // kv row d, 4 cols
        float ksd = kss[d];
        float av[4] = {a.x, a.y, a.z, a.w};
        float bv[4] = {b.x, b.y, b.z, b.w};
        #pragma unroll
        for (int i = 0; i < 4; ++i) {
            dn[i] += av[i] * ksd;
            #pragma unroll
            for (int j = 0; j < 4; ++j) acc[i][j] += av[i] * bv[j];
        }
    }

    float* Oh = out + ((size_t)head * Sn + (size_t)rc * 64) * Dn;
    #pragma unroll
    for (int i = 0; i < 4; ++i) {
        float inv = 1.0f / (dn[i] + FEPS);
        float4 r;
        r.x = acc[i][0] * inv; r.y = acc[i][1] * inv;
        r.z = acc[i][2] * inv; r.w = acc[i][3] * inv;
        *(float4*)&Oh[(size_t)(r0 + i) * Dn + e0] = r;
    }
}

extern "C" void kernel_launch(void* const* d_in, const int* in_sizes, int n_in,
                              void* d_out, int out_size, void* d_ws, size_t ws_size,
                              hipStream_t stream) {
    (void)in_sizes; (void)n_in; (void)out_size;
    const float* Q = (const float*)d_in[0];
    const float* K = (const float*)d_in[1];
    const float* V = (const float*)d_in[2];
    float* out = (float*)d_out;

    float* slots = (float*)d_ws;                         // [64][4160] final kv+ksum

    // pick the largest chunk count whose partial buffer fits in d_ws
    int chunks = 1;
    const int cand[4] = {16, 8, 4, 2};
    for (int ci = 0; ci < 4; ++ci) {
        if ((size_t)(1 + cand[ci]) * NHEAD * SLOT * sizeof(float) <= ws_size) {
            chunks = cand[ci];
            break;
        }
    }

    if (chunks > 1) {
        float* part = slots + (size_t)NHEAD * SLOT;      // [chunks][64][4160]
        hipLaunchKernelGGL(pass1, dim3(NHEAD, chunks), dim3(256), 0, stream,
                           K, V, part, Sn / chunks);
        hipLaunchKernelGGL(reduce_partials, dim3(NHEAD, (SLOT + 255) / 256), dim3(256), 0, stream,
                           part, slots, chunks);
    } else {
        // one block per head writes the final slot directly (no reduce needed)
        hipLaunchKernelGGL(pass1, dim3(NHEAD, 1), dim3(256), 0, stream,
                           K, V, slots, Sn);
    }
    hipLaunchKernelGGL(pass2, dim3(NHEAD, Sn / 64), dim3(256), 0, stream,
                       Q, slots, out);
}

// Round 6
// 93.336 us; speedup vs baseline: 5.2276x; 3.0270x over previous
//
#include <hip/hip_runtime.h>

#define FEPS 1e-5f

constexpr int Bn = 4, Hn = 16, Sn = 4096, Dn = 64;
constexpr int NHEAD = Bn * Hn;          // 64 heads
constexpr int STG_ROWS = 16;            // rows per stage (4 per wave)
constexpr int SLOT = Dn * Dn + Dn;      // 4160 floats: kv then ksum

// ---------------- Pass 1: partial kv = K^T V and k_sum over an S-chunk ----------------
// Register-staged, wave-private pipeline (T14 pattern, plain HIP, no inline asm):
//   per stage: global float4 -> regs (next stage) | compute current stage from
//   this wave's own LDS quarter | ds_write regs -> same quarter.
// DS ops are in-order per wave and quarters are wave-private => NO barriers in
// the loop. Compiler inserts precise counted vmcnt before ds_write (register
// dependency); ds_reads never wait on vmcnt. One __syncthreads before the
// final cross-wave reduction.
__global__ __launch_bounds__(256, 3) void pass1(const float* __restrict__ K,
                                                const float* __restrict__ V,
                                                float* __restrict__ part,
                                                int ch_s) {
    // union: staging {K 1024 | V 1024} floats  /  epilogue {redA 4096 | redB 4096 | ksred 256}
    __shared__ float lds[8448];   // 33 KB -> 4 blocks/CU (LDS); VGPR sets real cap

    const int head = blockIdx.x;
    const int chunk = blockIdx.y;
    const int t = threadIdx.x;
    const int w = t >> 6;                  // wave 0..3
    const int l = t & 63;
    const int d0 = (l >> 3) * 8;           // kv row-tile base (K dim)
    const int e0 = (l & 7) * 8;            // kv col-tile base (V dim)
    const int nstg = ch_s / STG_ROWS;

    const size_t base = ((size_t)head * Sn + (size_t)chunk * ch_s) * Dn;
    // wave w owns rows [w*4, w*4+4) of every 16-row stage
    const float* Kg = K + base + (size_t)w * 256 + l * 4;   // + st*1024 per stage
    const float* Vg = V + base + (size_t)w * 256 + l * 4;

    float* kq = &lds[w * 256];             // this wave's K quarter (4 rows x 64)
    float* vq = &lds[1024 + w * 256];      // this wave's V quarter

    float acc[8][8] = {};
    float ks[8] = {};

    // prologue: stage 0 into LDS
    {
        float4 kr = *(const float4*)Kg;
        float4 vr = *(const float4*)Vg;
        *(float4*)(kq + l * 4) = kr;
        *(float4*)(vq + l * 4) = vr;
    }

    for (int st = 0; st < nstg; ++st) {
        float4 kn, vn;
        const bool more = (st + 1 < nstg);
        if (more) {
            kn = *(const float4*)(Kg + (size_t)(st + 1) * 1024);
            vn = *(const float4*)(Vg + (size_t)(st + 1) * 1024);
        }
        // compute this wave's 4 rows of the current stage
        #pragma unroll
        for (int r = 0; r < 4; ++r) {
            float4 ka = *(const float4*)(kq + r * 64 + d0);
            float4 kc = *(const float4*)(kq + r * 64 + d0 + 4);
            float4 va = *(const float4*)(vq + r * 64 + e0);
            float4 vc = *(const float4*)(vq + r * 64 + e0 + 4);
            float kf[8] = {ka.x, ka.y, ka.z, ka.w, kc.x, kc.y, kc.z, kc.w};
            float vf[8] = {va.x, va.y, va.z, va.w, vc.x, vc.y, vc.z, vc.w};
            #pragma unroll
            for (int i = 0; i < 8; ++i) {
                ks[i] += kf[i];
                #pragma unroll
                for (int j = 0; j < 8; ++j) acc[i][j] += kf[i] * vf[j];
            }
        }
        // overwrite the just-consumed quarter with the next stage (in-order DS)
        if (more) {
            *(float4*)(kq + l * 4) = kn;
            *(float4*)(vq + l * 4) = vn;
        }
    }

    // ---- block reduction of the 4 wave partials (LDS reused as scratch) ----
    __syncthreads();
    float* redA = &lds[0];       // 4096 floats
    float* redB = &lds[4096];    // 4096 floats
    float* ksred = &lds[8192];   // 256 floats
    if (w == 0 || w == 1) {
        float* dst = (w == 0) ? redA : redB;
        #pragma unroll
        for (int i = 0; i < 8; ++i) {
            *(float4*)&dst[(d0 + i) * Dn + e0] =
                make_float4(acc[i][0], acc[i][1], acc[i][2], acc[i][3]);
            *(float4*)&dst[(d0 + i) * Dn + e0 + 4] =
                make_float4(acc[i][4], acc[i][5], acc[i][6], acc[i][7]);
        }
    }
    if ((l & 7) == 0) {
        #pragma unroll
        for (int i = 0; i < 8; ++i) ksred[w * Dn + d0 + i] = ks[i];
    }
    __syncthreads();
    if (w == 2 || w == 3) {
        float* dst = (w == 2) ? redA : redB;
        #pragma unroll
        for (int i = 0; i < 8; ++i)
            #pragma unroll
            for (int j = 0; j < 8; ++j) dst[(d0 + i) * Dn + e0 + j] += acc[i][j];
    }
    __syncthreads();

    float* slot = part + ((size_t)chunk * NHEAD + head) * SLOT;
    #pragma unroll
    for (int q = 0; q < 4; ++q) {
        int f = q * 1024 + t * 4;          // coalesced across lanes
        float4 a = *(const float4*)&redA[f];
        float4 b = *(const float4*)&redB[f];
        *(float4*)&slot[f] = make_float4(a.x + b.x, a.y + b.y, a.z + b.z, a.w + b.w);
    }
    if (t < Dn)
        slot[Dn * Dn + t] = ksred[0 * Dn + t] + ksred[1 * Dn + t] +
                            ksred[2 * Dn + t] + ksred[3 * Dn + t];
}

// ---------------- Reduce chunk-partials -> final slot layout [head][4096 kv + 64 ksum] ----------------
__global__ __launch_bounds__(256) void reduce_partials(const float* __restrict__ part,
                                                       float* __restrict__ slots,
                                                       int nchunks) {
    const int head = blockIdx.x;
    const int idx = blockIdx.y * 256 + threadIdx.x;
    if (idx >= SLOT) return;
    float s = 0.f;
    for (int c = 0; c < nchunks; ++c)
        s += part[((size_t)c * NHEAD + head) * SLOT + idx];
    slots[(size_t)head * SLOT + idx] = s;
}

// ---------------- Pass 2: out = (Q / (Q.ksum + eps)) @ kv ----------------
__global__ __launch_bounds__(256) void pass2(const float* __restrict__ Q,
                                             const float* __restrict__ slots,
                                             float* __restrict__ out) {
    const int head = blockIdx.x;
    const int rc = blockIdx.y;  // 64-row chunk
    const int t = threadIdx.x;
    const int ti = t >> 4, tj = t & 15;
    const int r0 = ti * 4, e0 = tj * 4;   // 4 rows x 4 cols per thread

    __shared__ float kvs[Dn][Dn];
    __shared__ float qT[Dn][68];          // transposed Q tile, padded
    __shared__ float kss[Dn];

    const float* kvh = slots + (size_t)head * SLOT;

    // stage kv (16KB; L2/L3-resident after reduce)
    const float4* kvsrc = (const float4*)kvh;
    float4* kvdst = (float4*)&kvs[0][0];
    #pragma unroll
    for (int kk = 0; kk < 4; ++kk) kvdst[t + 256 * kk] = kvsrc[t + 256 * kk];
    if (t < 16) ((float4*)kss)[t] = ((const float4*)(kvh + Dn * Dn))[t];

    // stage Q tile transposed: qT[d][row]
    const float4* Qsrc = (const float4*)(Q + ((size_t)head * Sn + (size_t)rc * 64) * Dn);
    #pragma unroll
    for (int kk = 0; kk < 4; ++kk) {
        int f = t + 256 * kk;
        int row = f >> 4, d4 = (f & 15) * 4;
        float4 q4 = Qsrc[f];
        qT[d4 + 0][row] = q4.x;
        qT[d4 + 1][row] = q4.y;
        qT[d4 + 2][row] = q4.z;
        qT[d4 + 3][row] = q4.w;
    }
    __syncthreads();

    float acc[4][4] = {};
    float dn[4] = {0.f, 0.f, 0.f, 0.f};
    #pragma unroll 8
    for (int d = 0; d < Dn; ++d) {
        float4 a = *(const float4*)&qT[d][r0];     // q for 4 rows at dim d
        float4 b = *(const float4*)&kvs[d][e0];    // kv row d, 4 cols
        float ksd = kss[d];
        float av[4] = {a.x, a.y, a.z, a.w};
        float bv[4] = {b.x, b.y, b.z, b.w};
        #pragma unroll
        for (int i = 0; i < 4; ++i) {
            dn[i] += av[i] * ksd;
            #pragma unroll
            for (int j = 0; j < 4; ++j) acc[i][j] += av[i] * bv[j];
        }
    }

    float* Oh = out + ((size_t)head * Sn + (size_t)rc * 64) * Dn;
    #pragma unroll
    for (int i = 0; i < 4; ++i) {
        float inv = 1.0f / (dn[i] + FEPS);
        float4 r;
        r.x = acc[i][0] * inv; r.y = acc[i][1] * inv;
        r.z = acc[i][2] * inv; r.w = acc[i][3] * inv;
        *(float4*)&Oh[(size_t)(r0 + i) * Dn + e0] = r;
    }
}

extern "C" void kernel_launch(void* const* d_in, const int* in_sizes, int n_in,
                              void* d_out, int out_size, void* d_ws, size_t ws_size,
                              hipStream_t stream) {
    (void)in_sizes; (void)n_in; (void)out_size;
    const float* Q = (const float*)d_in[0];
    const float* K = (const float*)d_in[1];
    const float* V = (const float*)d_in[2];
    float* out = (float*)d_out;

    float* slots = (float*)d_ws;                         // [64][4160] final kv+ksum

    // pick the largest chunk count whose partial buffer fits in d_ws
    int chunks = 1;
    const int cand[4] = {16, 8, 4, 2};
    for (int ci = 0; ci < 4; ++ci) {
        if ((size_t)(1 + cand[ci]) * NHEAD * SLOT * sizeof(float) <= ws_size) {
            chunks = cand[ci];
            break;
        }
    }

    if (chunks > 1) {
        float* part = slots + (size_t)NHEAD * SLOT;      // [chunks][64][4160]
        hipLaunchKernelGGL(pass1, dim3(NHEAD, chunks), dim3(256), 0, stream,
                           K, V, part, Sn / chunks);
        hipLaunchKernelGGL(reduce_partials, dim3(NHEAD, (SLOT + 255) / 256), dim3(256), 0, stream,
                           part, slots, chunks);
    } else {
        // one block per head writes the final slot directly (no reduce needed)
        hipLaunchKernelGGL(pass1, dim3(NHEAD, 1), dim3(256), 0, stream,
                           K, V, slots, Sn);
    }
    hipLaunchKernelGGL(pass2, dim3(NHEAD, Sn / 64), dim3(256), 0, stream,
                       Q, slots, out);
}